// Round 6
// baseline (302.880 us; speedup 1.0000x reference)
//
#include <hip/hip_runtime.h>
#include <cmath>

// ---------------------------------------------------------------------------
// PatchTST encoder layer w/ p-RoPE, MI355X (gfx950).  Round 6:
//  - flash rewritten around 32x32x16 MFMA (2x MACs/LDS-byte vs 16x16x32) and
//    the S^T trick: compute S^T = K.Q^T so the C/D layout (col=q, row=s)
//    makes P stores packed ds_write_b64 and P reads contiguous b128
//    (PV computed as O^T = V^T . P^T with P as B-operand).
//  - flash blocks: 128 thr (2 waves x 32 q-rows), single-buffer 24KB LDS.
//  - GEMMs/prep unchanged from round 5 (attribution: flash no longer masks
//    them in the top-5 profile).
// Fragment layouts (verified guide §3):
//   16x16x32: A[m=l15][k=quad*8+j]; C/D col=l15,row=quad*4+reg
//   32x32x16: A[m=lane&31][k=(lane>>5)*8+j]; B[k=(lane>>5)*8+j][n=lane&31];
//             C/D col=lane&31, row=(reg&3)+8*(reg>>2)+4*(lane>>5)
// ---------------------------------------------------------------------------

typedef __bf16 bf16_t;
typedef bf16_t bf16x4 __attribute__((ext_vector_type(4)));
typedef bf16_t bf16x8 __attribute__((ext_vector_type(8)));
typedef float floatx4 __attribute__((ext_vector_type(4)));
typedef float floatx16 __attribute__((ext_vector_type(16)));

#define MFMA(a, b, c) __builtin_amdgcn_mfma_f32_16x16x32_bf16((a), (b), (c), 0, 0, 0)
#define MFMA32(a, b, c) __builtin_amdgcn_mfma_f32_32x32x16_bf16((a), (b), (c), 0, 0, 0)
#define LOG2E 1.44269504088896340736f

__device__ __forceinline__ bf16_t f2bf(float f) { return (bf16_t)f; }

__device__ __forceinline__ void g2l16(const void* g, void* l) {
  __builtin_amdgcn_global_load_lds(
      (const __attribute__((address_space(1))) unsigned int*)g,
      (__attribute__((address_space(3))) unsigned int*)l, 16, 0, 0);
}

__device__ __forceinline__ void lds_fence() {
  asm volatile("s_waitcnt lgkmcnt(0)" ::: "memory");
}

// ---------------------------------------------------------------------------
// k_prep: all weight transposes (fp32 [R][C] -> bf16 [C][R]) + LN1, one grid.
// ---------------------------------------------------------------------------
struct PrepP {
  const float *wq, *wk, *wv, *wo, *w1, *w2;
  bf16_t *wqkvT, *woT, *w1T, *w2T;
  const float *hs, *g1, *be1;
  bf16_t* ni;
};

__global__ __launch_bounds__(256) void k_prep(PrepP p) {
  __shared__ float shm[32 * 33];
  const int bid = blockIdx.x;
  if (bid < 6912) {
    const float* in;
    bf16_t* out;
    int R, C, tx, ty;
    if (bid < 2304) {
      int m = bid / 576, lo = bid % 576;
      in = (m == 0) ? p.wq : (m == 1) ? p.wk : (m == 2) ? p.wv : p.wo;
      out = (m < 3) ? p.wqkvT + (size_t)m * 768 * 768 : p.woT;
      R = 768; C = 768; tx = lo % 24; ty = lo / 24;
    } else if (bid < 4608) {
      int lo = bid - 2304;
      in = p.w1; out = p.w1T; R = 768; C = 3072; tx = lo % 96; ty = lo / 96;
    } else {
      int lo = bid - 4608;
      in = p.w2; out = p.w2T; R = 3072; C = 768; tx = lo % 24; ty = lo / 24;
    }
    const int c0 = tx * 32, r0 = ty * 32;
    const int lx = threadIdx.x & 31, ly = threadIdx.x >> 5;
#pragma unroll
    for (int p4 = 0; p4 < 4; p4++) {
      int r = ly + p4 * 8;
      shm[r * 33 + lx] = in[(size_t)(r0 + r) * C + c0 + lx];
    }
    __syncthreads();
#pragma unroll
    for (int p4 = 0; p4 < 4; p4++) {
      int r = ly + p4 * 8;
      out[(size_t)(c0 + r) * R + r0 + lx] = f2bf(shm[lx * 33 + r]);
    }
  } else {
    const int row = bid - 6912;
    const float* xr = p.hs + (size_t)row * 768;
    const int t = threadIdx.x;
    float v0 = xr[t], v1 = xr[t + 256], v2 = xr[t + 512];
    float s = v0 + v1 + v2;
    float s2 = v0 * v0 + v1 * v1 + v2 * v2;
#pragma unroll
    for (int off = 32; off; off >>= 1) {
      s += __shfl_xor(s, off);
      s2 += __shfl_xor(s2, off);
    }
    const int w = t >> 6;
    if ((t & 63) == 0) { shm[w] = s; shm[4 + w] = s2; }
    __syncthreads();
    s = shm[0] + shm[1] + shm[2] + shm[3];
    s2 = shm[4] + shm[5] + shm[6] + shm[7];
    const float mu = s * (1.0f / 768.0f);
    const float var = s2 * (1.0f / 768.0f) - mu * mu;
    const float rstd = rsqrtf(var + 1e-5f);
    bf16_t* orow = p.ni + (size_t)row * 768;
    orow[t]       = f2bf((v0 - mu) * rstd * p.g1[t]       + p.be1[t]);
    orow[t + 256] = f2bf((v1 - mu) * rstd * p.g1[t + 256] + p.be1[t + 256]);
    orow[t + 512] = f2bf((v2 - mu) * rstd * p.g1[t + 512] + p.be1[t + 512]);
  }
}

// ---------------------------------------------------------------------------
// LayerNorm (LN3): fp32 in -> bf16 out, one block per row.
// ---------------------------------------------------------------------------
__global__ __launch_bounds__(256) void k_layernorm(
    const float* __restrict__ x, const float* __restrict__ g,
    const float* __restrict__ b, bf16_t* __restrict__ out) {
  const int row = blockIdx.x;
  const float* xr = x + (size_t)row * 768;
  const int t = threadIdx.x;
  float v0 = xr[t], v1 = xr[t + 256], v2 = xr[t + 512];
  float s = v0 + v1 + v2;
  float s2 = v0 * v0 + v1 * v1 + v2 * v2;
#pragma unroll
  for (int off = 32; off; off >>= 1) {
    s += __shfl_xor(s, off);
    s2 += __shfl_xor(s2, off);
  }
  __shared__ float ra[4], rb[4];
  const int w = t >> 6;
  if ((t & 63) == 0) { ra[w] = s; rb[w] = s2; }
  __syncthreads();
  s = ra[0] + ra[1] + ra[2] + ra[3];
  s2 = rb[0] + rb[1] + rb[2] + rb[3];
  const float mu = s * (1.0f / 768.0f);
  const float var = s2 * (1.0f / 768.0f) - mu * mu;
  const float rstd = rsqrtf(var + 1e-5f);
  bf16_t* orow = out + (size_t)row * 768;
  orow[t]       = f2bf((v0 - mu) * rstd * g[t]       + b[t]);
  orow[t + 256] = f2bf((v1 - mu) * rstd * g[t + 256] + b[t + 256]);
  orow[t + 512] = f2bf((v2 - mu) * rstd * g[t + 512] + b[t + 512]);
}

// ---------------------------------------------------------------------------
// 128x128-tile bf16 MFMA GEMM (QKV mode 0, FFN1 mode 2). m97 structure.
// ---------------------------------------------------------------------------
struct GemmP {
  const bf16_t* A;
  const bf16_t* Bt;
  int M, N, K, mode;
  const float* bias0;
  const float* bias1;
  const float* bias2;
  float* outF;
  bf16_t* outB0;
  bf16_t* outB1;
  bf16_t* outB2;
};

__global__ __launch_bounds__(256, 3) void k_gemm(GemmP p) {
  __shared__ bf16_t lds[18432];  // 36 KiB: lA@0[8192], lB@8192[8192] + scratch
  const int tid = threadIdx.x;
  const int lane = tid & 63, wave = tid >> 6;
  const int quad = lane >> 4, l15 = lane & 15;
  const int wm = (wave >> 1) * 64, wn = (wave & 1) * 64;
  const int m0 = blockIdx.y * 128, n0 = blockIdx.x * 128;

  const char* gA[4];
  const char* gB[4];
#pragma unroll
  for (int pp = 0; pp < 4; pp++) {
    int slot = wave * 256 + pp * 64 + lane;
    int r = slot >> 3;
    int c8 = ((slot & 7) ^ (r & 7)) << 3;
    gA[pp] = (const char*)(p.A + (size_t)(m0 + r) * p.K + c8);
    gB[pp] = (const char*)(p.Bt + (size_t)(n0 + r) * p.K + c8);
  }

  int offA[4], offB[4];
#pragma unroll
  for (int i = 0; i < 4; i++) {
    int ra = wm + i * 16 + l15;
    offA[i] = ra * 64 + ((quad * 8) ^ ((ra & 7) << 3));
    int rb = wn + i * 16 + l15;
    offB[i] = rb * 64 + ((quad * 8) ^ ((rb & 7) << 3));
  }

  const floatx4 z4 = {0.f, 0.f, 0.f, 0.f};
  floatx4 acc[4][4];
#pragma unroll
  for (int i = 0; i < 4; i++)
#pragma unroll
    for (int j = 0; j < 4; j++) acc[i][j] = z4;

  const int KT = p.K >> 6;
  bf16_t* Ad = lds + wave * 2048;
  bf16_t* Bd = lds + 8192 + wave * 2048;

  for (int kt = 0; kt < KT; kt++) {
    const size_t kb = (size_t)kt * 128;  // bytes
#pragma unroll
    for (int pp = 0; pp < 4; pp++) {
      g2l16(gA[pp] + kb, Ad + pp * 512);
      g2l16(gB[pp] + kb, Bd + pp * 512);
    }
    __syncthreads();
#pragma unroll
    for (int ks = 0; ks < 2; ks++) {
      bf16x8 af[4], bfr[4];
#pragma unroll
      for (int i = 0; i < 4; i++) {
        af[i] = *(const bf16x8*)(lds + (offA[i] ^ (ks * 32)));
        bfr[i] = *(const bf16x8*)(lds + 8192 + (offB[i] ^ (ks * 32)));
      }
#pragma unroll
      for (int i = 0; i < 4; i++)
#pragma unroll
        for (int j = 0; j < 4; j++) acc[i][j] = MFMA(af[i], bfr[j], acc[i][j]);
    }
    __syncthreads();
  }

  char* scr = (char*)lds + wave * 9216;

  if (p.mode == 0) {
    const int gnw = n0 + wn;
    const int region = gnw / 768;  // block-uniform
    const int rem = gnw - region * 768;
    const int h = rem >> 6;
    const int b = (m0 + wm) >> 11;
    const int t0 = (m0 + wm) & 2047;
    const float* bias = (region == 0) ? p.bias0 : (region == 1 ? p.bias1 : p.bias2);
    float bb[4];
#pragma unroll
    for (int j = 0; j < 4; j++) bb[j] = bias[h * 64 + j * 16 + l15];
    bf16_t* sb = (bf16_t*)scr;  // [64][72]
    if (region < 2) {
      const float scale = (region == 0) ? 0.125f * LOG2E : 1.0f;
      const float inv_ts = exp2f(-(float)l15 * (13.287712379549449f / 32.0f));
#pragma unroll
      for (int i = 0; i < 4; i++) {
#pragma unroll
        for (int reg = 0; reg < 4; reg++) {
          int tl = i * 16 + quad * 4 + reg;
          float sn, cs;
          __sincosf((float)(t0 + tl) * inv_ts, &sn, &cs);
          float v0 = (acc[i][0][reg] + bb[0]) * scale;
          float v1 = (acc[i][1][reg] + bb[1]) * scale;
          float v2 = (acc[i][2][reg] + bb[2]) * scale;
          float v3 = (acc[i][3][reg] + bb[3]) * scale;
          sb[tl * 72 + l15]      = f2bf(v0 * cs - v2 * sn);
          sb[tl * 72 + 16 + l15] = f2bf(v1);
          sb[tl * 72 + 32 + l15] = f2bf(v2 * cs + v0 * sn);
          sb[tl * 72 + 48 + l15] = f2bf(v3);
        }
      }
      __syncthreads();
      bf16_t* outp = (region == 0) ? p.outB0 : p.outB1;
      bf16_t* ob = outp + (((size_t)(b * 12 + h) * 2048 + t0) << 6);
#pragma unroll
      for (int pp = 0; pp < 8; pp++) {
        int row = pp * 8 + (lane >> 3), ch = (lane & 7) << 3;
        *(bf16x8*)(ob + row * 64 + ch) = *(const bf16x8*)&sb[row * 72 + ch];
      }
    } else {
#pragma unroll
      for (int i = 0; i < 4; i++)
#pragma unroll
        for (int j = 0; j < 4; j++)
#pragma unroll
          for (int reg = 0; reg < 4; reg++)
            sb[(j * 16 + l15) * 72 + i * 16 + quad * 4 + reg] =
                f2bf(acc[i][j][reg] + bb[j]);
      __syncthreads();
      bf16_t* ob = p.outB2 + (((size_t)(b * 12 + h)) << 17) + t0;
#pragma unroll
      for (int pp = 0; pp < 8; pp++) {
        int d = pp * 8 + (lane >> 3), ch = (lane & 7) << 3;
        *(bf16x8*)(ob + (size_t)d * 2048 + ch) = *(const bf16x8*)&sb[d * 72 + ch];
      }
    }
  } else {  // mode 2: FFN1 + exact GELU -> bf16
    bf16_t* sb = (bf16_t*)scr;  // [64][72]
    float bb[4];
#pragma unroll
    for (int j = 0; j < 4; j++) bb[j] = p.bias0[n0 + wn + j * 16 + l15];
#pragma unroll
    for (int i = 0; i < 4; i++)
#pragma unroll
      for (int j = 0; j < 4; j++)
#pragma unroll
        for (int reg = 0; reg < 4; reg++) {
          int tl = i * 16 + quad * 4 + reg;
          float x = acc[i][j][reg] + bb[j];
          float gv = 0.5f * x * (1.0f + erff(x * 0.70710678118654752f));
          sb[tl * 72 + j * 16 + l15] = f2bf(gv);
        }
    __syncthreads();
#pragma unroll
    for (int pp = 0; pp < 8; pp++) {
      int row = pp * 8 + (lane >> 3), ch = (lane & 7) << 3;
      *(bf16x8*)(p.outB0 + (size_t)(m0 + wm + row) * p.N + n0 + wn + ch) =
          *(const bf16x8*)&sb[row * 72 + ch];
    }
  }
}

// ---------------------------------------------------------------------------
// 64x64-tile GEMM for N=768 layers (WO, FFN2): fp32 out = acc + bias + resid.
// ---------------------------------------------------------------------------
__global__ __launch_bounds__(256, 4) void k_gemm64(
    const bf16_t* __restrict__ A, const bf16_t* __restrict__ Bt, int N, int K,
    const float* __restrict__ bias, const float* __restrict__ resid,
    float* __restrict__ outF) {
  __shared__ bf16_t lds[16384];  // 32 KiB
  const int tid = threadIdx.x;
  const int lane = tid & 63, wave = tid >> 6;
  const int quad = lane >> 4, l15 = lane & 15;
  const int wm = (wave >> 1) * 32, wn = (wave & 1) * 32;
  const int m0 = blockIdx.y * 64, n0 = blockIdx.x * 64;

  const char* gA[4];
  const char* gB[4];
#pragma unroll
  for (int pp = 0; pp < 4; pp++) {
    int slot = wave * 256 + pp * 64 + lane;
    int r = slot >> 4;
    int c = ((slot & 15) ^ (r & 7)) << 3;  // elems
    gA[pp] = (const char*)(A + (size_t)(m0 + r) * K + c);
    gB[pp] = (const char*)(Bt + (size_t)(n0 + r) * K + c);
  }

  const floatx4 z4 = {0.f, 0.f, 0.f, 0.f};
  floatx4 acc[2][2];
#pragma unroll
  for (int i = 0; i < 2; i++)
#pragma unroll
    for (int j = 0; j < 2; j++) acc[i][j] = z4;

  const int KT = K >> 7;
  bf16_t* Ad = lds + wave * 2048;
  bf16_t* Bd = lds + 8192 + wave * 2048;

  for (int kt = 0; kt < KT; kt++) {
    const size_t kb = (size_t)kt * 256;  // bytes (128 elems)
#pragma unroll
    for (int pp = 0; pp < 4; pp++) {
      g2l16(gA[pp] + kb, Ad + pp * 512);
      g2l16(gB[pp] + kb, Bd + pp * 512);
    }
    __syncthreads();
#pragma unroll
    for (int ks = 0; ks < 4; ks++) {
      bf16x8 af[2], bfr[2];
#pragma unroll
      for (int i = 0; i < 2; i++) {
        int ra = wm + i * 16 + l15;
        af[i] = *(const bf16x8*)(lds + ra * 128 +
                                 (((ks * 4 + quad) ^ (ra & 7)) << 3));
        int rb = wn + i * 16 + l15;
        bfr[i] = *(const bf16x8*)(lds + 8192 + rb * 128 +
                                  (((ks * 4 + quad) ^ (rb & 7)) << 3));
      }
#pragma unroll
      for (int i = 0; i < 2; i++)
#pragma unroll
        for (int j = 0; j < 2; j++) acc[i][j] = MFMA(af[i], bfr[j], acc[i][j]);
    }
    __syncthreads();
  }

  float* s4 = (float*)lds + wave * 1024;
#pragma unroll
  for (int i = 0; i < 2; i++)
#pragma unroll
    for (int j = 0; j < 2; j++)
#pragma unroll
      for (int reg = 0; reg < 4; reg++)
        s4[(i * 16 + quad * 4 + reg) * 32 + j * 16 + l15] = acc[i][j][reg];
  __syncthreads();
#pragma unroll
  for (int pp = 0; pp < 4; pp++) {
    int row = pp * 8 + (lane >> 3);
    int c4 = (lane & 7) * 4;
    floatx4 v = *(const floatx4*)&s4[row * 32 + c4];
    size_t goff = (size_t)(m0 + wm + row) * N + n0 + wn + c4;
    floatx4 rv = *(const floatx4*)(resid + goff);
    floatx4 bv = *(const floatx4*)(bias + n0 + wn + c4);
    *(floatx4*)(outF + goff) = v + rv + bv;
  }
}

// ---------------------------------------------------------------------------
// Flash attention v2: 32x32x16 MFMA, S^T trick, packed P path.
// Block = 128 thr (2 waves x 32 q-rows), kv-tile 64, single-buffer 24KB LDS.
// S^T = K.Q^T (Q = B-operand, registers); P stored [q][s] via b64 writes;
// O^T = V^T.P^T (P = B-operand, b128 reads from [q][s] rows).
// Swizzle: addr(row,e) = row*64 + (((e>>3) ^ (row&7))<<3) + (e&7).
// ---------------------------------------------------------------------------
__global__ __launch_bounds__(128, 2) void k_flash(
    const bf16_t* __restrict__ qh, const bf16_t* __restrict__ kh,
    const bf16_t* __restrict__ vt, const float* __restrict__ ab,
    bf16_t* __restrict__ attnA) {
  __shared__ bf16_t sm[12288];  // 24 KiB
  bf16_t* lK = sm;              // [64s][64d]
  bf16_t* lV = sm + 4096;       // [64d][64s]
  bf16_t* lP = sm + 8192;       // 2 waves x [32q][64s]

  const int tid = threadIdx.x, lane = tid & 63, wave = tid >> 6;
  const int l31 = lane & 31, lh = lane >> 5;
  const int sw = l31 & 7;
  const int qtile = blockIdx.x, bh = blockIdx.y;
  const int h = bh % 12, bq = bh / 12;
  const int qw = qtile * 64 + wave * 32;  // wave's first q row

  const bf16_t* Qb = qh + (size_t)bh * 2048 * 64;
  const bf16_t* Kb = kh + (size_t)bh * 2048 * 64;
  const bf16_t* Vb = vt + (size_t)bh * 64 * 2048;

  // staging source pointers: 4 x 16B per thread per tensor (512 slots)
  const char* gK[4];
  const char* gV[4];
#pragma unroll
  for (int pp = 0; pp < 4; pp++) {
    int slot = pp * 128 + tid;
    int r = slot >> 3;
    int c8 = ((slot & 7) ^ (r & 7)) << 3;
    gK[pp] = (const char*)(Kb + r * 64 + c8);            // +kv*8192 B
    gV[pp] = (const char*)(Vb + (size_t)r * 2048 + c8);  // +kv*128 B
  }

  // Q as B-operand: lane holds Q[qw+l31][d = ks*16 + lh*8 + j]
  bf16x8 qf[4];
#pragma unroll
  for (int ks = 0; ks < 4; ks++)
    qf[ks] = *(const bf16x8*)(Qb + (size_t)(qw + l31) * 64 + ks * 16 + lh * 8);

  const floatx16 z16 = {0.f, 0.f, 0.f, 0.f, 0.f, 0.f, 0.f, 0.f,
                        0.f, 0.f, 0.f, 0.f, 0.f, 0.f, 0.f, 0.f};
  floatx16 oacc0 = z16, oacc1 = z16;
  float l_part = 0.f;

  const float bc_same = ab[h * 2] * LOG2E;
  const float bc_diff = ab[h * 2 + 1] * LOG2E;
  const int myv = qtile >> 1;

  bf16_t* myP = lP + wave * 2048;

  for (int kv = 0; kv < 32; kv++) {
    const size_t kb = (size_t)kv * 8192, vb = (size_t)kv * 128;
#pragma unroll
    for (int pp = 0; pp < 4; pp++) {
      g2l16(gK[pp] + kb, lK + pp * 1024 + wave * 512);
      g2l16(gV[pp] + vb, lV + pp * 1024 + wave * 512);
    }
    __syncthreads();  // staging visible (drains vmcnt)

    // S^T[s][q]: A = K-frag (lK rows), B = Q (regs). 2 s-tiles x 4 ksteps.
    floatx16 sacc0 = z16, sacc1 = z16;
#pragma unroll
    for (int ks = 0; ks < 4; ks++) {
      const int ch = ((2 * ks + lh) ^ sw) << 3;
      sacc0 = MFMA32(*(const bf16x8*)(lK + l31 * 64 + ch), qf[ks], sacc0);
      sacc1 = MFMA32(*(const bf16x8*)(lK + (32 + l31) * 64 + ch), qf[ks], sacc1);
    }

    // P = exp2(s' + bc); packed b64 stores into [q=l31][s] rows
    const float bc = ((kv >> 1) == myv) ? bc_same : bc_diff;
#pragma unroll
    for (int st = 0; st < 2; st++) {
      const floatx16& sv = st ? sacc1 : sacc0;
#pragma unroll
      for (int g = 0; g < 4; g++) {
        bf16x4 pk;
#pragma unroll
        for (int r = 0; r < 4; r++) {
          float pv = exp2f(sv[g * 4 + r] + bc);
          l_part += pv;
          pk[r] = f2bf(pv);
        }
        // s0 = st*32 + 8g + 4lh -> chunk st*4+g, half lh
        *(bf16x4*)(myP + l31 * 64 + (((st * 4 + g) ^ sw) << 3) + 4 * lh) = pk;
      }
    }
    lds_fence();

    // O^T[d][q] += V^T-frag x P-frag
#pragma unroll
    for (int ks = 0; ks < 4; ks++) {
      const int ch = ((2 * ks + lh) ^ sw) << 3;
      const bf16x8 pf = *(const bf16x8*)(myP + l31 * 64 + ch);
      oacc0 = MFMA32(*(const bf16x8*)(lV + l31 * 64 + ch), pf, oacc0);
      oacc1 = MFMA32(*(const bf16x8*)(lV + (32 + l31) * 64 + ch), pf, oacc1);
    }
    __syncthreads();  // all waves done reading lK/lV before restage
  }

  // l over full 64 s: partner lane holds the other half for same q
  const float l_tot = l_part + __shfl_xor(l_part, 32);
  const float inv = 1.0f / l_tot;

  // stage O^T -> [q][d] rows (reuse myP), then coalesced global stores
  lds_fence();
#pragma unroll
  for (int dt = 0; dt < 2; dt++) {
    const floatx16& ov = dt ? oacc1 : oacc0;
#pragma unroll
    for (int g = 0; g < 4; g++) {
      bf16x4 pk;
#pragma unroll
      for (int r = 0; r < 4; r++) pk[r] = f2bf(ov[g * 4 + r] * inv);
      *(bf16x4*)(myP + l31 * 64 + (((dt * 4 + g) ^ sw) << 3) + 4 * lh) = pk;
    }
  }
  lds_fence();
#pragma unroll
  for (int ps = 0; ps < 4; ps++) {
    int rr = ps * 8 + (lane >> 3), c = lane & 7;
    bf16x8 v = *(const bf16x8*)(myP + rr * 64 + (((c ^ (rr & 7)) << 3)));
    *(bf16x8*)(attnA + ((size_t)(bq * 2048 + qw + rr)) * 768 + h * 64 + c * 8) = v;
  }
}

// ---------------------------------------------------------------------------
extern "C" void kernel_launch(void* const* d_in, const int* in_sizes, int n_in,
                              void* d_out, int out_size, void* d_ws,
                              size_t ws_size, hipStream_t stream) {
  const float* hs  = (const float*)d_in[0];
  const float* wq  = (const float*)d_in[1];
  const float* bq  = (const float*)d_in[2];
  const float* wk  = (const float*)d_in[3];
  const float* bk  = (const float*)d_in[4];
  const float* wv  = (const float*)d_in[5];
  const float* bv  = (const float*)d_in[6];
  const float* wo  = (const float*)d_in[7];
  const float* bo  = (const float*)d_in[8];
  const float* ab  = (const float*)d_in[9];
  const float* g1  = (const float*)d_in[10];
  const float* be1 = (const float*)d_in[11];
  const float* g3  = (const float*)d_in[12];
  const float* be3 = (const float*)d_in[13];
  const float* w1  = (const float*)d_in[14];
  const float* b1  = (const float*)d_in[15];
  const float* w2  = (const float*)d_in[16];
  const float* b2  = (const float*)d_in[17];

  char* ws = (char*)d_ws;
  size_t off = 0;
  auto alloc = [&](size_t bytes) -> void* {
    void* p = ws + off;
    off += (bytes + 255) & ~(size_t)255;
    return p;
  };
  bf16_t* wqkvT = (bf16_t*)alloc((size_t)2304 * 768 * 2);
  bf16_t* woT   = (bf16_t*)alloc((size_t)768 * 768 * 2);
  bf16_t* w1T   = (bf16_t*)alloc((size_t)3072 * 768 * 2);
  bf16_t* w2T   = (bf16_t*)alloc((size_t)768 * 3072 * 2);
  bf16_t* ni    = (bf16_t*)alloc((size_t)4096 * 768 * 2);
  bf16_t* qhB   = (bf16_t*)alloc((size_t)24 * 2048 * 64 * 2);
  bf16_t* khB   = (bf16_t*)alloc((size_t)24 * 2048 * 64 * 2);
  bf16_t* vtB   = (bf16_t*)alloc((size_t)24 * 64 * 2048 * 2);
  bf16_t* attnA = (bf16_t*)alloc((size_t)4096 * 768 * 2);
  float*  resid1 = (float*)alloc((size_t)4096 * 768 * 4);
  bf16_t* ffn1o = qhB;  // overlay: q/k/v/attn region dead by FFN1 time

  // prep: all transposes + LN1, one dispatch
  PrepP pp = {wq, wk, wv, wo, w1, w2, wqkvT, woT, w1T, w2T, hs, g1, be1, ni};
  k_prep<<<11008, 256, 0, stream>>>(pp);

  // QKV (fused, N=2304): bias, q*0.125*log2e, p-RoPE, head-layout scatter
  GemmP gqkv = {ni, wqkvT, 4096, 2304, 768, 0,
                bq, bk, bv, nullptr, qhB, khB, vtB};
  k_gemm<<<dim3(18, 32), 256, 0, stream>>>(gqkv);

  // flash attention v2
  k_flash<<<dim3(32, 24), 128, 0, stream>>>(qhB, khB, vtB, ab, attnA);

  // attn @ wo + bo + residual(hidden) -> resid1 (fp32)
  k_gemm64<<<dim3(12, 64), 256, 0, stream>>>(attnA, woT, 768, 768, bo, hs,
                                             resid1);

  // LN3
  k_layernorm<<<4096, 256, 0, stream>>>(resid1, g3, be3, ni);

  // FFN1 + exact GELU -> bf16
  GemmP gf1 = {ni, w1T, 4096, 3072, 768, 2,
               b1, nullptr, nullptr, nullptr, ffn1o, nullptr, nullptr};
  k_gemm<<<dim3(24, 32), 256, 0, stream>>>(gf1);

  // FFN2 + b2 + residual -> d_out (fp32 [4096][768])
  k_gemm64<<<dim3(12, 64), 256, 0, stream>>>(ffn1o, w2T, 768, 3072, b2,
                                             resid1, (float*)d_out);
}